// Round 1
// baseline (768.524 us; speedup 1.0000x reference)
//
#include <hip/hip_runtime.h>
#include <math.h>

#define C 256
#define S 16
#define CR 64          // C / R, R = 4
#define NREP 8         // replicated global accumulators (contention reduction)

// ---------------- Kernel 1: segment sums + counts ----------------
// Block = 128 threads. Thread t exclusively owns channels {2t, 2t+1} of the
// LDS accumulator for ALL 16 segments -> no atomics / no syncs in hot loop.
__global__ __launch_bounds__(128) void k_segsum(
    const float* __restrict__ x, const int* __restrict__ idx,
    float* __restrict__ psum, int* __restrict__ pcnt, int nrows)
{
    __shared__ float ls[S][C];
    __shared__ int   lc[S];
    const int t = threadIdx.x;

    #pragma unroll
    for (int i = t; i < S * C; i += 128) (&ls[0][0])[i] = 0.0f;
    if (t < S) lc[t] = 0;
    __syncthreads();

    const float2* __restrict__ x2 = reinterpret_cast<const float2*>(x);
    for (int row = blockIdx.x; row < nrows; row += gridDim.x) {
        const int s = idx[row];                 // uniform -> scalar load
        float2 v = x2[row * (C / 2) + t];       // 8 B/lane, coalesced 1 KB/row
        float2* p = reinterpret_cast<float2*>(&ls[s][2 * t]);
        float2 cur = *p;
        cur.x += v.x; cur.y += v.y;
        *p = cur;
        if (t == 0) lc[s]++;
    }
    __syncthreads();

    const int rep = blockIdx.x & (NREP - 1);
    float* gs = psum + rep * S * C;
    int*   gc = pcnt + rep * S;
    for (int i = t; i < S * C; i += 128) atomicAdd(&gs[i], (&ls[0][0])[i]);
    if (t < S) atomicAdd(&gc[t], lc[t]);
}

// ---------------- Kernel 2: reduce replicas + tiny SE MLP ----------------
// Single block, 256 threads. ~1 MFLOP total.
__global__ __launch_bounds__(256) void k_mlp(
    const float* __restrict__ psum, const int* __restrict__ pcnt,
    const float* __restrict__ w1, const float* __restrict__ w2,
    float* __restrict__ gate)
{
    __shared__ float sm[S][C];     // segment means
    __shared__ float h[S][CR];     // hidden
    __shared__ float cnt[S];
    const int t = threadIdx.x;

    if (t < S) {
        int c = 0;
        #pragma unroll
        for (int r = 0; r < NREP; r++) c += pcnt[r * S + t];
        cnt[t] = fmaxf((float)c, 1.0f);
    }
    __syncthreads();

    for (int i = t; i < S * C; i += 256) {
        float v = 0.0f;
        #pragma unroll
        for (int r = 0; r < NREP; r++) v += psum[r * S * C + i];
        sm[i / C][i % C] = v / cnt[i / C];
    }
    __syncthreads();

    // h = relu(sm @ w1) ; w1 is (C, CR) row-major
    for (int o = t; o < S * CR; o += 256) {
        const int s = o / CR, j = o % CR;
        float acc = 0.0f;
        #pragma unroll 4
        for (int k = 0; k < C; k++) acc += sm[s][k] * w1[k * CR + j];
        h[s][j] = fmaxf(acc, 0.0f);
    }
    __syncthreads();

    // gate = sigmoid(h @ w2) ; w2 is (CR, C) row-major
    for (int o = t; o < S * C; o += 256) {
        const int s = o / C, j = o % C;
        float acc = 0.0f;
        #pragma unroll
        for (int k = 0; k < CR; k++) acc += h[s][k] * w2[k * C + j];
        gate[o] = 1.0f / (1.0f + expf(-acc));
    }
}

// ---------------- Kernel 3: out = x * gate[idx] ----------------
// One wave (64 lanes) per row, float4/lane; 4 rows per 256-thread block iter.
// gate (16 KB) is read straight from global: fits L1 per CU -> no LDS needed.
__global__ __launch_bounds__(256) void k_mod(
    const float* __restrict__ x, const int* __restrict__ idx,
    const float* __restrict__ gate, float* __restrict__ out, int nrows)
{
    const int l    = threadIdx.x & 63;
    const int wrow = threadIdx.x >> 6;   // wave id in block: 0..3
    const float4* __restrict__ x4 = reinterpret_cast<const float4*>(x);
    const float4* __restrict__ g4 = reinterpret_cast<const float4*>(gate);
    float4* __restrict__ o4 = reinterpret_cast<float4*>(out);

    for (int row = blockIdx.x * 4 + wrow; row < nrows; row += gridDim.x * 4) {
        const int s = idx[row];                  // wave-uniform -> broadcast
        float4 v = x4[row * (C / 4) + l];        // 16 B/lane, 1 KB/row/wave
        const float4 g = g4[s * (C / 4) + l];    // L1-resident
        v.x *= g.x; v.y *= g.y; v.z *= g.z; v.w *= g.w;
        o4[row * (C / 4) + l] = v;
    }
}

extern "C" void kernel_launch(void* const* d_in, const int* in_sizes, int n_in,
                              void* d_out, int out_size, void* d_ws, size_t ws_size,
                              hipStream_t stream)
{
    const float* x   = (const float*)d_in[0];
    const int*   idx = (const int*)  d_in[1];   // harness passes integers as int32
    const float* w1  = (const float*)d_in[2];
    const float* w2  = (const float*)d_in[3];
    float* out = (float*)d_out;
    const int nrows = in_sizes[1];

    // ws layout: [psum: NREP*S*C floats][pcnt: NREP*S ints][gate: S*C floats]
    float* psum = (float*)d_ws;
    int*   pcnt = (int*)(psum + NREP * S * C);
    float* gate = (float*)(pcnt + NREP * S);

    const size_t zero_bytes = NREP * S * C * sizeof(float) + NREP * S * sizeof(int);
    hipMemsetAsync(d_ws, 0, zero_bytes, stream);

    k_segsum<<<2048, 128, 0, stream>>>(x, idx, psum, pcnt, nrows);
    k_mlp<<<1, 256, 0, stream>>>(psum, pcnt, w1, w2, gate);
    k_mod<<<2048, 256, 0, stream>>>(x, idx, gate, out, nrows);
}